// Round 1
// baseline (132.422 us; speedup 1.0000x reference)
//
#include <hip/hip_runtime.h>
#include <math.h>

namespace {

constexpr int B = 8;
constexpr int N = 8192;
constexpr int D = 1024;
constexpr int E = 4;
constexpr int BN = B * N;

// ---------------------------------------------------------------------------
// Kernel 1: logits = x @ W^T + b ; probs = softmax(logits) (fp64 accumulate)
// Output layout: probs_t[b][e][n]  (transposed, so K2 reads contiguous rows)
// One wave (64 lanes) per token; each lane loads 4 float4 of x (coalesced).
// ---------------------------------------------------------------------------
__global__ __launch_bounds__(256) void probs_kernel(
    const float* __restrict__ x,     // [BN, D]
    const float* __restrict__ W,     // [E, D]
    const float* __restrict__ bias,  // [E]
    float* __restrict__ probs_t)     // [B, E, N]
{
    __shared__ float s_W[E * D];  // 16 KB
    {
        const float4* W4 = reinterpret_cast<const float4*>(W);
        float4* sW4 = reinterpret_cast<float4*>(s_W);
        for (int i = threadIdx.x; i < E * D / 4; i += blockDim.x) sW4[i] = W4[i];
    }
    __syncthreads();

    const int lane = threadIdx.x & 63;
    const int waves_per_block = blockDim.x >> 6;
    const int wid = blockIdx.x * waves_per_block + (threadIdx.x >> 6);
    const int nwaves = gridDim.x * waves_per_block;

    const float4* sW4 = reinterpret_cast<const float4*>(s_W);
    const double b0 = bias[0], b1 = bias[1], b2 = bias[2], b3 = bias[3];

    for (int token = wid; token < BN; token += nwaves) {
        const float4* xv = reinterpret_cast<const float4*>(x) + (size_t)token * (D / 4);
        double a0 = 0.0, a1 = 0.0, a2 = 0.0, a3 = 0.0;
#pragma unroll
        for (int c = 0; c < D / 4 / 64; ++c) {
            const int idx = lane + 64 * c;
            const float4 xc = xv[idx];
            const float4 w0 = sW4[0 * (D / 4) + idx];
            const float4 w1 = sW4[1 * (D / 4) + idx];
            const float4 w2 = sW4[2 * (D / 4) + idx];
            const float4 w3 = sW4[3 * (D / 4) + idx];
            a0 += (double)xc.x * w0.x + (double)xc.y * w0.y +
                  (double)xc.z * w0.z + (double)xc.w * w0.w;
            a1 += (double)xc.x * w1.x + (double)xc.y * w1.y +
                  (double)xc.z * w1.z + (double)xc.w * w1.w;
            a2 += (double)xc.x * w2.x + (double)xc.y * w2.y +
                  (double)xc.z * w2.z + (double)xc.w * w2.w;
            a3 += (double)xc.x * w3.x + (double)xc.y * w3.y +
                  (double)xc.z * w3.z + (double)xc.w * w3.w;
        }
        // wave64 butterfly reduction (all lanes end with the full sum)
#pragma unroll
        for (int off = 32; off >= 1; off >>= 1) {
            a0 += __shfl_xor(a0, off, 64);
            a1 += __shfl_xor(a1, off, 64);
            a2 += __shfl_xor(a2, off, 64);
            a3 += __shfl_xor(a3, off, 64);
        }
        const double l0 = a0 + b0, l1 = a1 + b1, l2 = a2 + b2, l3 = a3 + b3;
        const double m = fmax(fmax(l0, l1), fmax(l2, l3));
        const double e0 = exp(l0 - m), e1 = exp(l1 - m);
        const double e2 = exp(l2 - m), e3 = exp(l3 - m);
        const double Z = e0 + e1 + e2 + e3;
        if (lane < E) {
            const double p = (lane == 0) ? e0 : (lane == 1) ? e1 : (lane == 2) ? e2 : e3;
            const int brow = token / N;
            const int n = token - brow * N;
            probs_t[((size_t)brow * E + lane) * N + n] = (float)(p / Z);
        }
    }
}

// ---------------------------------------------------------------------------
// Kernel 2: capacity-constrained expert-preferred routing. One block per row.
// Exact reproduction of stable argsort(-r) top-k semantics via radix-select
// on orderable fp32 key bits + stable (index-ordered) tie handling.
// ---------------------------------------------------------------------------
__global__ __launch_bounds__(1024) void route_kernel(
    const float* __restrict__ probs_t,  // [B, E, N]
    float* __restrict__ out)            // [2*B*N]: mask (as float), then probs
{
    constexpr int TPB = 1024;
    constexpr int ITEMS = N / TPB;  // 8 contiguous tokens per thread

    __shared__ unsigned int s_key[N];        // 32 KB
    __shared__ unsigned char s_exp[N];       // 8 KB, 255 = unassigned
    __shared__ unsigned int s_hist[256];     // 1 KB
    __shared__ unsigned int s_scan[TPB];     // 4 KB
    __shared__ unsigned int s_sel[2];        // {chosen bin, new rem}

    const int b = blockIdx.x;
    const int t = threadIdx.x;

    for (int u = 0; u < ITEMS; ++u) s_exp[t * ITEMS + u] = 255;
    __syncthreads();

    const float caps[E] = {0.1f, 0.15f, 0.25f, 0.5f};
    int nun = N;  // unassigned count (uniform across block)

    for (int j = E - 1; j >= 0; --j) {
        int kk = (int)floorf(caps[j] * (float)N);
        if (kk > nun) kk = nun;

        // Load this expert's probs as orderable uint keys into LDS.
        const float* pj = probs_t + ((size_t)b * E + j) * N;
        for (int u = 0; u < ITEMS; ++u) {
            const int i = t * ITEMS + u;
            const unsigned int bits = __float_as_uint(pj[i]);
            s_key[i] = (bits & 0x80000000u) ? ~bits : (bits | 0x80000000u);
        }
        __syncthreads();

        // Radix-select the kk-th largest key among unassigned tokens.
        unsigned int prefix = 0;
        unsigned int rem = (unsigned int)kk;
        for (int shift = 24; shift >= 0; shift -= 8) {
            if (t < 256) s_hist[t] = 0;
            __syncthreads();
            for (int u = 0; u < ITEMS; ++u) {
                const int i = t * ITEMS + u;
                if (s_exp[i] == 255) {
                    const unsigned int key = s_key[i];
                    const bool match = (shift == 24) || ((key >> (shift + 8)) == prefix);
                    if (match) atomicAdd(&s_hist[(key >> shift) & 255u], 1u);
                }
            }
            __syncthreads();
            // Reverse (suffix) inclusive scan over 256 bins, high bin first.
            if (t < 256) s_scan[t] = s_hist[255 - t];
            __syncthreads();
            for (int off = 1; off < 256; off <<= 1) {
                unsigned int v = 0;
                if (t < 256 && t >= off) v = s_scan[t - off];
                __syncthreads();
                if (t < 256) s_scan[t] += v;
                __syncthreads();
            }
            if (t < 256) {
                const int bin = 255 - t;
                const unsigned int incl = s_scan[t];
                const unsigned int excl = incl - s_hist[bin];
                if (excl < rem && incl >= rem) {
                    s_sel[0] = (unsigned int)bin;
                    s_sel[1] = rem - excl;
                }
            }
            __syncthreads();
            prefix = (prefix << 8) | s_sel[0];
            rem = s_sel[1];
        }
        const unsigned int T = prefix;  // exact key of kk-th largest
        // rem = number of (key == T) tokens to take, in ascending token index.

        // Stable rank of ==T matches: per-thread count, then block prefix scan.
        unsigned int local = 0;
        for (int u = 0; u < ITEMS; ++u) {
            const int i = t * ITEMS + u;
            if (s_exp[i] == 255 && s_key[i] == T) ++local;
        }
        s_scan[t] = local;
        __syncthreads();
        for (int off = 1; off < TPB; off <<= 1) {
            const unsigned int v = (t >= off) ? s_scan[t - off] : 0u;
            __syncthreads();
            s_scan[t] += v;
            __syncthreads();
        }
        unsigned int taken = s_scan[t] - local;  // exclusive prefix

        for (int u = 0; u < ITEMS; ++u) {
            const int i = t * ITEMS + u;
            if (s_exp[i] != 255) continue;
            const unsigned int key = s_key[i];
            if (key > T) {
                s_exp[i] = (unsigned char)j;
            } else if (key == T) {
                if (taken < rem) s_exp[i] = (unsigned char)j;
                ++taken;
            }
        }
        nun -= kk;
        __syncthreads();
    }

    // Emit token_mask (as float) and expert_probs.
    float* out_mask = out;
    float* out_p = out + (size_t)BN;
    for (int u = 0; u < ITEMS; ++u) {
        const int i = t * ITEMS + u;
        int e = s_exp[i];
        if (e == 255) e = 0;  // unassigned -> expert 0 (matches reference)
        out_mask[(size_t)b * N + i] = (float)e;
        out_p[(size_t)b * N + i] = probs_t[((size_t)b * E + e) * N + i];
    }
}

}  // namespace

extern "C" void kernel_launch(void* const* d_in, const int* in_sizes, int n_in,
                              void* d_out, int out_size, void* d_ws, size_t ws_size,
                              hipStream_t stream) {
    const float* x = (const float*)d_in[0];     // [B, N, D]
    const float* W = (const float*)d_in[1];     // [E, D]
    const float* bias = (const float*)d_in[2];  // [E]
    float* out = (float*)d_out;                 // [2*B*N] floats
    float* probs_t = (float*)d_ws;              // [B, E, N] fp32, 1 MB

    // K1: 2048 blocks x 256 threads = 8192 waves, 8 tokens per wave.
    probs_kernel<<<2048, 256, 0, stream>>>(x, W, bias, probs_t);
    // K2: one block per batch row.
    route_kernel<<<B, 1024, 0, stream>>>(probs_t, out);
}

// Round 2
// 91.148 us; speedup vs baseline: 1.4528x; 1.4528x over previous
//
#include <hip/hip_runtime.h>
#include <math.h>

namespace {

constexpr int B = 8;
constexpr int N = 8192;
constexpr int D = 1024;
constexpr int E = 4;
constexpr int BN = B * N;

__device__ __forceinline__ unsigned int orderkey(float p) {
    // all probs are positive finite floats
    return __float_as_uint(p) | 0x80000000u;
}

// ---------------------------------------------------------------------------
// Kernel 1: logits = x @ W^T + b ; probs = softmax(logits), all fp64.
// Wave per token. Value-split butterfly (7 f64 shuffles) distributes the 4
// logits so each lane owns expert j = ((lane&1)<<1)|((lane>>1)&1); softmax is
// computed once per 4-lane group (1 exp call per lane instead of 4).
// ---------------------------------------------------------------------------
__global__ __launch_bounds__(256) void probs_kernel(
    const float* __restrict__ x,     // [BN, D]
    const float* __restrict__ W,     // [E, D]
    const float* __restrict__ bias,  // [E]
    float* __restrict__ probs_t)     // [B, E, N]
{
    __shared__ float s_W[E * D];  // 16 KB
    {
        const float4* W4 = reinterpret_cast<const float4*>(W);
        float4* sW4w = reinterpret_cast<float4*>(s_W);
        for (int i = threadIdx.x; i < E * D / 4; i += blockDim.x) sW4w[i] = W4[i];
    }
    __syncthreads();

    const int lane = threadIdx.x & 63;
    const int wid = blockIdx.x * (blockDim.x >> 6) + (threadIdx.x >> 6);
    const int nwaves = gridDim.x * (blockDim.x >> 6);
    const int j = ((lane & 1) << 1) | ((lane >> 1) & 1);  // expert owned by this lane
    const double bj = (double)bias[j];

    const float4* sW4 = reinterpret_cast<const float4*>(s_W);
    const float4* x4 = reinterpret_cast<const float4*>(x);

    int token = wid;
    float4 xr0 = {0,0,0,0}, xr1 = {0,0,0,0}, xr2 = {0,0,0,0}, xr3 = {0,0,0,0};
    if (token < BN) {
        const float4* xv = x4 + (size_t)token * (D / 4);
        xr0 = xv[lane]; xr1 = xv[lane + 64]; xr2 = xv[lane + 128]; xr3 = xv[lane + 192];
    }

    for (; token < BN; token += nwaves) {
        const int nxt = token + nwaves;
        float4 xn0 = {0,0,0,0}, xn1 = {0,0,0,0}, xn2 = {0,0,0,0}, xn3 = {0,0,0,0};
        if (nxt < BN) {  // prefetch next token while computing this one
            const float4* xv = x4 + (size_t)nxt * (D / 4);
            xn0 = xv[lane]; xn1 = xv[lane + 64]; xn2 = xv[lane + 128]; xn3 = xv[lane + 192];
        }

        double a0 = 0.0, a1 = 0.0, a2 = 0.0, a3 = 0.0;
        {
            const float4 xc[4] = {xr0, xr1, xr2, xr3};
#pragma unroll
            for (int c = 0; c < 4; ++c) {
                const int idx = lane + 64 * c;
                const double xx = xc[c].x, xy = xc[c].y, xz = xc[c].z, xw = xc[c].w;
                const float4 w0 = sW4[0 * (D / 4) + idx];
                const float4 w1 = sW4[1 * (D / 4) + idx];
                const float4 w2 = sW4[2 * (D / 4) + idx];
                const float4 w3 = sW4[3 * (D / 4) + idx];
                a0 += xx * (double)w0.x + xy * (double)w0.y + xz * (double)w0.z + xw * (double)w0.w;
                a1 += xx * (double)w1.x + xy * (double)w1.y + xz * (double)w1.z + xw * (double)w1.w;
                a2 += xx * (double)w2.x + xy * (double)w2.y + xz * (double)w2.z + xw * (double)w2.w;
                a3 += xx * (double)w3.x + xy * (double)w3.y + xz * (double)w3.z + xw * (double)w3.w;
            }
        }

        // Value-split butterfly reduction: 7 f64 shuffles total.
        // Step 1 (xor 1): even lanes end owning (A0,A1) pair-sums, odd (A2,A3).
        {
            const double v = (lane & 1) ? a0 : a2;
            const double w = (lane & 1) ? a1 : a3;
            const double sv = __shfl_xor(v, 1, 64);
            const double sw = __shfl_xor(w, 1, 64);
            const double s0 = (lane & 1) ? (a2 + sv) : (a0 + sv);
            const double s1 = (lane & 1) ? (a3 + sw) : (a1 + sw);
            // Step 2 (xor 2): each lane ends owning one logit (expert j above).
            const double tt = (lane & 2) ? s0 : s1;
            const double st = __shfl_xor(tt, 2, 64);
            double s = (lane & 2) ? (s1 + st) : (s0 + st);
            // Steps 3-6: full reduce over remaining lanes.
            s += __shfl_xor(s, 4, 64);
            s += __shfl_xor(s, 8, 64);
            s += __shfl_xor(s, 16, 64);
            s += __shfl_xor(s, 32, 64);

            const double l = s + bj;
            // softmax within each 4-lane group (all groups hold the same data)
            double m = fmax(l, __shfl_xor(l, 1, 64));
            m = fmax(m, __shfl_xor(m, 2, 64));
            const double eV = exp(l - m);
            double Z = eV + __shfl_xor(eV, 1, 64);
            Z += __shfl_xor(Z, 2, 64);
            if (lane < 4) {
                const int brow = token >> 13;
                const int n = token & (N - 1);
                probs_t[((size_t)brow * E + j) * N + n] = (float)(eV / Z);
            }
        }

        xr0 = xn0; xr1 = xn1; xr2 = xn2; xr3 = xn3;
    }
}

// ---------------------------------------------------------------------------
// Kernel 2: capacity-constrained expert-preferred routing. One block per row.
// Per expert: one monotone value-bucket histogram (4096 bins, spread atomics),
// 2-barrier hierarchical suffix scan, assign strictly-above buckets, gather
// boundary-bucket candidates (typically ~8-30), finish with a single-wave
// bitonic sort on (key desc, idx asc) — exact stable top-k semantics.
// Rare fallback (>64 candidates): exact 256-bin MSB radix + stable tie rank.
// ---------------------------------------------------------------------------
__global__ __launch_bounds__(1024) void route_kernel(
    const float* __restrict__ probs_t,  // [B, E, N]
    float* __restrict__ out)            // [2*B*N]: mask (as float), then probs
{
    constexpr int TPB = 1024;
    constexpr int ITEMS = N / TPB;  // 8
    constexpr int NBKT = 4096;
    constexpr int CMAX = 64;

    __shared__ unsigned short s_bkt[N];      // 16 KB
    __shared__ unsigned char s_exp[N];       // 8 KB, 255 = unassigned
    __shared__ unsigned int s_hist[NBKT];    // 16 KB (fallback reuses bins 0-255)
    __shared__ unsigned int s_cand[CMAX];
    __shared__ unsigned int s_ckey[CMAX];
    __shared__ unsigned int s_wsum[32];      // [0:16) wave totals, [16:32) excl
    __shared__ unsigned int s_sel[3];        // {selected bin, rem, cand count}

    const int b = blockIdx.x;
    const int t = threadIdx.x;
    const int lane = t & 63;
    const int wv = t >> 6;

    for (int u = 0; u < ITEMS; ++u) s_exp[t * ITEMS + u] = 255;

    const int kcap[E] = {819, 1228, 2048, 4096};  // floor(cap_j * N)
    int nun = N;

    for (int j = E - 1; j >= 0; --j) {
        const int kk = min(kcap[j], nun);
        const float* pj = probs_t + ((size_t)b * E + j) * N;

        for (int u = 0; u < NBKT / TPB; ++u) s_hist[t + u * TPB] = 0;
        if (t == 0) s_sel[2] = 0;
        __syncthreads();

        // monotone bucket + histogram over unassigned
        for (int u = 0; u < ITEMS; ++u) {
            const int i = t * ITEMS + u;
            const float p = pj[i];
            int bk = (int)(p * 4096.0f);
            bk = bk > 4095 ? 4095 : (bk < 0 ? 0 : bk);
            s_bkt[i] = (unsigned short)bk;
            if (s_exp[i] == 255) atomicAdd(&s_hist[bk], 1u);
        }
        __syncthreads();

        // hierarchical suffix scan over 4096 bins; thread t owns bins [4t,4t+4)
        const unsigned int h0 = s_hist[4 * t], h1 = s_hist[4 * t + 1];
        const unsigned int h2 = s_hist[4 * t + 2], h3 = s_hist[4 * t + 3];
        const unsigned int lsum = h0 + h1 + h2 + h3;
        unsigned int sfx = lsum;
#pragma unroll
        for (int off = 1; off < 64; off <<= 1) {
            const unsigned int vv = __shfl_down(sfx, off, 64);
            if (lane + off < 64) sfx += vv;
        }
        if (lane == 0) s_wsum[wv] = sfx;
        __syncthreads();
        if (t < 16) {  // exclusive suffix over 16 wave totals (separate slots, no hazard)
            unsigned int acc = 0;
            for (int w2 = t + 1; w2 < 16; ++w2) acc += s_wsum[w2];
            s_wsum[16 + t] = acc;
        }
        __syncthreads();
        {
            unsigned int run = (sfx - lsum) + s_wsum[16 + wv];  // sum of bins above mine
            const unsigned int hh[4] = {h0, h1, h2, h3};
#pragma unroll
            for (int bi = 3; bi >= 0; --bi) {
                const unsigned int h = hh[bi];
                if (run < (unsigned)kk && run + h >= (unsigned)kk) {
                    s_sel[0] = (unsigned)(4 * t + bi);
                    s_sel[1] = (unsigned)kk - run;
                }
                run += h;
            }
        }
        __syncthreads();
        const int Bstar = (int)s_sel[0];
        const unsigned int rem = s_sel[1];

        // assign strictly-above buckets; gather boundary-bucket candidates
        for (int u = 0; u < ITEMS; ++u) {
            const int i = t * ITEMS + u;
            if (s_exp[i] != 255) continue;
            const int bk = s_bkt[i];
            if (bk > Bstar) {
                s_exp[i] = (unsigned char)j;
            } else if (bk == Bstar) {
                const unsigned int pos = atomicAdd(&s_sel[2], 1u);
                if (pos < CMAX) { s_cand[pos] = (unsigned int)i; s_ckey[pos] = orderkey(pj[i]); }
            }
        }
        __syncthreads();
        const unsigned int c = s_sel[2];

        if (rem == c) {
            // whole boundary bucket is taken
            for (int u = 0; u < ITEMS; ++u) {
                const int i = t * ITEMS + u;
                if (s_exp[i] == 255 && s_bkt[i] == Bstar) s_exp[i] = (unsigned char)j;
            }
            __syncthreads();
        } else if (c <= CMAX) {
            // single-wave bitonic: ascending on (~key, idx) == (key desc, idx asc)
            if (wv == 0) {
                unsigned int key = 0u, idx = 0xFFFFFFFFu;
                if (lane < (int)c) { key = s_ckey[lane]; idx = s_cand[lane]; }
                unsigned long long v = ((unsigned long long)(~key) << 32) | idx;
                for (int k2 = 2; k2 <= 64; k2 <<= 1) {
                    for (int jj = k2 >> 1; jj >= 1; jj >>= 1) {
                        const unsigned long long pv = __shfl_xor(v, jj, 64);
                        const bool up = ((lane & k2) == 0);
                        const bool lower = ((lane & jj) == 0);
                        if (lower == up) v = (v < pv) ? v : pv;
                        else             v = (v > pv) ? v : pv;
                    }
                }
                if (lane < (int)rem) {
                    const unsigned int tok = (unsigned int)(v & 0xFFFFFFFFu);
                    s_exp[tok] = (unsigned char)j;
                }
            }
            __syncthreads();
        } else {
            // rare fallback: exact 256-bin MSB radix-select over unassigned
            unsigned int prefix = 0, remR = rem;
            for (int shift = 24; shift >= 0; shift -= 8) {
                if (t < 256) s_hist[t] = 0;
                __syncthreads();
                for (int u = 0; u < ITEMS; ++u) {
                    const int i = t * ITEMS + u;
                    if (s_exp[i] != 255) continue;
                    const unsigned int key = orderkey(pj[i]);
                    if (shift == 24 || (key >> (shift + 8)) == prefix)
                        atomicAdd(&s_hist[(key >> shift) & 255u], 1u);
                }
                __syncthreads();
                if (wv == 0) {  // suffix scan of 256 bins in one wave
                    const unsigned int g0 = s_hist[4 * lane], g1 = s_hist[4 * lane + 1];
                    const unsigned int g2 = s_hist[4 * lane + 2], g3 = s_hist[4 * lane + 3];
                    const unsigned int ls = g0 + g1 + g2 + g3;
                    unsigned int sx = ls;
#pragma unroll
                    for (int off = 1; off < 64; off <<= 1) {
                        const unsigned int vv = __shfl_down(sx, off, 64);
                        if (lane + off < 64) sx += vv;
                    }
                    unsigned int rr = sx - ls;
                    const unsigned int gg[4] = {g0, g1, g2, g3};
#pragma unroll
                    for (int bi = 3; bi >= 0; --bi) {
                        const unsigned int h = gg[bi];
                        if (rr < remR && rr + h >= remR) {
                            s_sel[0] = (unsigned)(4 * lane + bi);
                            s_sel[1] = remR - rr;
                        }
                        rr += h;
                    }
                }
                __syncthreads();
                prefix = (prefix << 8) | s_sel[0];
                remR = s_sel[1];
            }
            const unsigned int T = prefix;
            // stable tie rank in token order
            unsigned int local = 0;
            for (int u = 0; u < ITEMS; ++u) {
                const int i = t * ITEMS + u;
                if (s_exp[i] == 255 && orderkey(pj[i]) == T) ++local;
            }
            unsigned int inc = local;
#pragma unroll
            for (int off = 1; off < 64; off <<= 1) {
                const unsigned int vv = __shfl_up(inc, off, 64);
                if (lane >= off) inc += vv;
            }
            if (lane == 63) s_wsum[wv] = inc;
            __syncthreads();
            if (t < 16) {
                unsigned int a2 = 0;
                for (int w2 = 0; w2 < t; ++w2) a2 += s_wsum[w2];
                s_wsum[16 + t] = a2;
            }
            __syncthreads();
            unsigned int taken = (inc - local) + s_wsum[16 + wv];
            for (int u = 0; u < ITEMS; ++u) {
                const int i = t * ITEMS + u;
                if (s_exp[i] != 255) continue;
                const unsigned int key = orderkey(pj[i]);
                if (key > T) {
                    s_exp[i] = (unsigned char)j;
                } else if (key == T) {
                    if (taken < remR) s_exp[i] = (unsigned char)j;
                    ++taken;
                }
            }
            __syncthreads();
        }
        nun -= kk;
    }

    // emit token_mask (as float) and expert_probs
    float* out_mask = out;
    float* out_p = out + (size_t)BN;
    for (int u = 0; u < ITEMS; ++u) {
        const int i = t * ITEMS + u;
        int e = s_exp[i];
        if (e == 255) e = 0;
        out_mask[(size_t)b * N + i] = (float)e;
        out_p[(size_t)b * N + i] = probs_t[((size_t)b * E + e) * N + i];
    }
}

}  // namespace

extern "C" void kernel_launch(void* const* d_in, const int* in_sizes, int n_in,
                              void* d_out, int out_size, void* d_ws, size_t ws_size,
                              hipStream_t stream) {
    const float* x = (const float*)d_in[0];     // [B, N, D]
    const float* W = (const float*)d_in[1];     // [E, D]
    const float* bias = (const float*)d_in[2];  // [E]
    float* out = (float*)d_out;                 // [2*B*N] floats
    float* probs_t = (float*)d_ws;              // [B, E, N] fp32, 1 MB

    probs_kernel<<<2048, 256, 0, stream>>>(x, W, bias, probs_t);
    route_kernel<<<B, 1024, 0, stream>>>(probs_t, out);
}

// Round 3
// 86.356 us; speedup vs baseline: 1.5334x; 1.0555x over previous
//
#include <hip/hip_runtime.h>
#include <math.h>

namespace {

constexpr int B = 8;
constexpr int N = 8192;
constexpr int D = 1024;
constexpr int E = 4;
constexpr int BN = B * N;

__device__ __forceinline__ unsigned int orderkey(float p) {
    return __float_as_uint(p) | 0x80000000u;  // positive floats
}

// f64 exp, |x| <= ~8: ln2 hi/lo range reduction + degree-12 Taylor.
// Relative error ~2e-16 (vs selection-relevant gaps ~1e-4). ~15 f64 FMAs.
__device__ __forceinline__ double fast_exp64(double x) {
    const double L2E    = 1.4426950408889634074;
    const double LN2_HI = 6.93147180369123816490e-01;
    const double LN2_LO = 1.90821492927058770002e-10;
    const double nd = rint(x * L2E);
    double r = fma(-nd, LN2_HI, x);
    r = fma(-nd, LN2_LO, r);
    double p = 1.0 / 479001600.0;
    p = fma(p, r, 1.0 / 39916800.0);
    p = fma(p, r, 1.0 / 3628800.0);
    p = fma(p, r, 1.0 / 362880.0);
    p = fma(p, r, 1.0 / 40320.0);
    p = fma(p, r, 1.0 / 5040.0);
    p = fma(p, r, 1.0 / 720.0);
    p = fma(p, r, 1.0 / 120.0);
    p = fma(p, r, 1.0 / 24.0);
    p = fma(p, r, 1.0 / 6.0);
    p = fma(p, r, 0.5);
    p = fma(p, r, 1.0);
    p = fma(p, r, 1.0);
    const long long sc = ((long long)(1023 + (int)nd)) << 52;
    return p * __longlong_as_double(sc);
}

// ---------------------------------------------------------------------------
// Kernel 1: logits (f64 FMA vs LDS-resident f64 W) + deferred batched softmax.
// Block = 256 threads = 4 waves; block owns 64 consecutive tokens (16/wave).
// Phase 1: wave-per-token dot product, value-split butterfly, park logits in
// LDS. Phase 2: one (token, expert) per thread -> exp/div tail fully parallel.
// ---------------------------------------------------------------------------
__global__ __launch_bounds__(256) void probs_kernel(
    const float* __restrict__ x,     // [BN, D]
    const float* __restrict__ W,     // [E, D]
    const float* __restrict__ bias,  // [E]
    float* __restrict__ probs_t)     // [B, E, N]
{
    // W as f64, split so each lane's 16B chunk sits at stride 16B (no bank
    // conflicts on ds_read_b128): quad q of expert e -> WA={w0,w1}, WB={w2,w3}.
    __shared__ double2 s_WA[E][D / 4];  // 16 KB
    __shared__ double2 s_WB[E][D / 4];  // 16 KB
    __shared__ double s_l[64][4];       // 2 KB  per-token logits

    {
        const float4* W4 = reinterpret_cast<const float4*>(W);
        for (int i = threadIdx.x; i < E * D / 4; i += 256) {
            const int e = i >> 8, q = i & 255;
            const float4 w = W4[i];
            s_WA[e][q] = make_double2((double)w.x, (double)w.y);
            s_WB[e][q] = make_double2((double)w.z, (double)w.w);
        }
    }
    __syncthreads();

    const int lane = threadIdx.x & 63;
    const int wv = threadIdx.x >> 6;
    const int tok0 = blockIdx.x * 64 + wv * 16;  // 16 tokens per wave
    const int j = ((lane & 1) << 1) | ((lane >> 1) & 1);  // expert after split

    const float4* x4 = reinterpret_cast<const float4*>(x);

    float4 c0, c1, c2, c3;
    {
        const float4* xv = x4 + (size_t)tok0 * (D / 4);
        c0 = xv[lane]; c1 = xv[lane + 64]; c2 = xv[lane + 128]; c3 = xv[lane + 192];
    }

    for (int k = 0; k < 16; ++k) {
        float4 n0, n1, n2, n3;
        if (k < 15) {  // prefetch next token
            const float4* xv = x4 + (size_t)(tok0 + k + 1) * (D / 4);
            n0 = xv[lane]; n1 = xv[lane + 64]; n2 = xv[lane + 128]; n3 = xv[lane + 192];
        }

        double a0 = 0.0, a1 = 0.0, a2 = 0.0, a3 = 0.0;
#define CHUNK(XC, CI)                                                          \
        {                                                                      \
            const int idx = lane + 64 * (CI);                                  \
            const double xx = (XC).x, xy = (XC).y, xz = (XC).z, xw = (XC).w;   \
            const double2 wA0 = s_WA[0][idx], wB0 = s_WB[0][idx];              \
            const double2 wA1 = s_WA[1][idx], wB1 = s_WB[1][idx];              \
            const double2 wA2 = s_WA[2][idx], wB2 = s_WB[2][idx];              \
            const double2 wA3 = s_WA[3][idx], wB3 = s_WB[3][idx];              \
            a0 = fma(xx, wA0.x, a0); a0 = fma(xy, wA0.y, a0);                  \
            a0 = fma(xz, wB0.x, a0); a0 = fma(xw, wB0.y, a0);                  \
            a1 = fma(xx, wA1.x, a1); a1 = fma(xy, wA1.y, a1);                  \
            a1 = fma(xz, wB1.x, a1); a1 = fma(xw, wB1.y, a1);                  \
            a2 = fma(xx, wA2.x, a2); a2 = fma(xy, wA2.y, a2);                  \
            a2 = fma(xz, wB2.x, a2); a2 = fma(xw, wB2.y, a2);                  \
            a3 = fma(xx, wA3.x, a3); a3 = fma(xy, wA3.y, a3);                  \
            a3 = fma(xz, wB3.x, a3); a3 = fma(xw, wB3.y, a3);                  \
        }
        CHUNK(c0, 0) CHUNK(c1, 1) CHUNK(c2, 2) CHUNK(c3, 3)
#undef CHUNK

        // Value-split butterfly: 7 f64 shuffles; lanes 0-3 end with experts
        // {0,2,1,3} respectively (lane's expert = j above).
        {
            const double v = (lane & 1) ? a0 : a2;
            const double w = (lane & 1) ? a1 : a3;
            const double sv = __shfl_xor(v, 1, 64);
            const double sw = __shfl_xor(w, 1, 64);
            const double s0 = (lane & 1) ? (a2 + sv) : (a0 + sv);
            const double s1 = (lane & 1) ? (a3 + sw) : (a1 + sw);
            const double tt = (lane & 2) ? s0 : s1;
            const double st = __shfl_xor(tt, 2, 64);
            double s = (lane & 2) ? (s1 + st) : (s0 + st);
            s += __shfl_xor(s, 4, 64);
            s += __shfl_xor(s, 8, 64);
            s += __shfl_xor(s, 16, 64);
            s += __shfl_xor(s, 32, 64);
            if (lane < 4) s_l[wv * 16 + k][j] = s;
        }

        c0 = n0; c1 = n1; c2 = n2; c3 = n3;
    }
    __syncthreads();

    // Phase 2: thread t -> (token t>>2, expert t&3). exp/div 256-wide parallel.
    {
        const int tok = threadIdx.x >> 2;
        const int e = threadIdx.x & 3;
        const double l0 = s_l[tok][0] + (double)bias[0];
        const double l1 = s_l[tok][1] + (double)bias[1];
        const double l2 = s_l[tok][2] + (double)bias[2];
        const double l3 = s_l[tok][3] + (double)bias[3];
        const double m = fmax(fmax(l0, l1), fmax(l2, l3));
        const double le = (e == 0) ? l0 : (e == 1) ? l1 : (e == 2) ? l2 : l3;
        const double ex = fast_exp64(le - m);
        double Z = ex + __shfl_xor(ex, 1, 64);
        Z += __shfl_xor(Z, 2, 64);
        const double p = ex / Z;
        const int token = blockIdx.x * 64 + tok;
        const int brow = token >> 13;
        const int n = token & (N - 1);
        probs_t[((size_t)brow * E + e) * N + n] = (float)p;
    }
}

// ---------------------------------------------------------------------------
// Kernel 2: capacity-constrained expert-preferred routing (verified, as R2).
// ---------------------------------------------------------------------------
__global__ __launch_bounds__(1024) void route_kernel(
    const float* __restrict__ probs_t,  // [B, E, N]
    float* __restrict__ out)            // [2*B*N]: mask (as float), then probs
{
    constexpr int TPB = 1024;
    constexpr int ITEMS = N / TPB;  // 8
    constexpr int NBKT = 4096;
    constexpr int CMAX = 64;

    __shared__ unsigned short s_bkt[N];      // 16 KB
    __shared__ unsigned char s_exp[N];       // 8 KB, 255 = unassigned
    __shared__ unsigned int s_hist[NBKT];    // 16 KB
    __shared__ unsigned int s_cand[CMAX];
    __shared__ unsigned int s_ckey[CMAX];
    __shared__ unsigned int s_wsum[32];
    __shared__ unsigned int s_sel[3];

    const int b = blockIdx.x;
    const int t = threadIdx.x;
    const int lane = t & 63;
    const int wv = t >> 6;

    for (int u = 0; u < ITEMS; ++u) s_exp[t * ITEMS + u] = 255;

    const int kcap[E] = {819, 1228, 2048, 4096};
    int nun = N;

    for (int j = E - 1; j >= 0; --j) {
        const int kk = min(kcap[j], nun);
        const float* pj = probs_t + ((size_t)b * E + j) * N;

        for (int u = 0; u < NBKT / TPB; ++u) s_hist[t + u * TPB] = 0;
        if (t == 0) s_sel[2] = 0;
        __syncthreads();

        for (int u = 0; u < ITEMS; ++u) {
            const int i = t * ITEMS + u;
            const float p = pj[i];
            int bk = (int)(p * 4096.0f);
            bk = bk > 4095 ? 4095 : (bk < 0 ? 0 : bk);
            s_bkt[i] = (unsigned short)bk;
            if (s_exp[i] == 255) atomicAdd(&s_hist[bk], 1u);
        }
        __syncthreads();

        const unsigned int h0 = s_hist[4 * t], h1 = s_hist[4 * t + 1];
        const unsigned int h2 = s_hist[4 * t + 2], h3 = s_hist[4 * t + 3];
        const unsigned int lsum = h0 + h1 + h2 + h3;
        unsigned int sfx = lsum;
#pragma unroll
        for (int off = 1; off < 64; off <<= 1) {
            const unsigned int vv = __shfl_down(sfx, off, 64);
            if (lane + off < 64) sfx += vv;
        }
        if (lane == 0) s_wsum[wv] = sfx;
        __syncthreads();
        if (t < 16) {
            unsigned int acc = 0;
            for (int w2 = t + 1; w2 < 16; ++w2) acc += s_wsum[w2];
            s_wsum[16 + t] = acc;
        }
        __syncthreads();
        {
            unsigned int run = (sfx - lsum) + s_wsum[16 + wv];
            const unsigned int hh[4] = {h0, h1, h2, h3};
#pragma unroll
            for (int bi = 3; bi >= 0; --bi) {
                const unsigned int h = hh[bi];
                if (run < (unsigned)kk && run + h >= (unsigned)kk) {
                    s_sel[0] = (unsigned)(4 * t + bi);
                    s_sel[1] = (unsigned)kk - run;
                }
                run += h;
            }
        }
        __syncthreads();
        const int Bstar = (int)s_sel[0];
        const unsigned int rem = s_sel[1];

        for (int u = 0; u < ITEMS; ++u) {
            const int i = t * ITEMS + u;
            if (s_exp[i] != 255) continue;
            const int bk = s_bkt[i];
            if (bk > Bstar) {
                s_exp[i] = (unsigned char)j;
            } else if (bk == Bstar) {
                const unsigned int pos = atomicAdd(&s_sel[2], 1u);
                if (pos < CMAX) { s_cand[pos] = (unsigned int)i; s_ckey[pos] = orderkey(pj[i]); }
            }
        }
        __syncthreads();
        const unsigned int c = s_sel[2];

        if (rem == c) {
            for (int u = 0; u < ITEMS; ++u) {
                const int i = t * ITEMS + u;
                if (s_exp[i] == 255 && s_bkt[i] == Bstar) s_exp[i] = (unsigned char)j;
            }
            __syncthreads();
        } else if (c <= CMAX) {
            if (wv == 0) {
                unsigned int key = 0u, idx = 0xFFFFFFFFu;
                if (lane < (int)c) { key = s_ckey[lane]; idx = s_cand[lane]; }
                unsigned long long v = ((unsigned long long)(~key) << 32) | idx;
                for (int k2 = 2; k2 <= 64; k2 <<= 1) {
                    for (int jj = k2 >> 1; jj >= 1; jj >>= 1) {
                        const unsigned long long pv = __shfl_xor(v, jj, 64);
                        const bool up = ((lane & k2) == 0);
                        const bool lower = ((lane & jj) == 0);
                        if (lower == up) v = (v < pv) ? v : pv;
                        else             v = (v > pv) ? v : pv;
                    }
                }
                if (lane < (int)rem) {
                    const unsigned int tok = (unsigned int)(v & 0xFFFFFFFFu);
                    s_exp[tok] = (unsigned char)j;
                }
            }
            __syncthreads();
        } else {
            unsigned int prefix = 0, remR = rem;
            for (int shift = 24; shift >= 0; shift -= 8) {
                if (t < 256) s_hist[t] = 0;
                __syncthreads();
                for (int u = 0; u < ITEMS; ++u) {
                    const int i = t * ITEMS + u;
                    if (s_exp[i] != 255) continue;
                    const unsigned int key = orderkey(pj[i]);
                    if (shift == 24 || (key >> (shift + 8)) == prefix)
                        atomicAdd(&s_hist[(key >> shift) & 255u], 1u);
                }
                __syncthreads();
                if (wv == 0) {
                    const unsigned int g0 = s_hist[4 * lane], g1 = s_hist[4 * lane + 1];
                    const unsigned int g2 = s_hist[4 * lane + 2], g3 = s_hist[4 * lane + 3];
                    const unsigned int ls = g0 + g1 + g2 + g3;
                    unsigned int sx = ls;
#pragma unroll
                    for (int off = 1; off < 64; off <<= 1) {
                        const unsigned int vv = __shfl_down(sx, off, 64);
                        if (lane + off < 64) sx += vv;
                    }
                    unsigned int rr = sx - ls;
                    const unsigned int gg[4] = {g0, g1, g2, g3};
#pragma unroll
                    for (int bi = 3; bi >= 0; --bi) {
                        const unsigned int h = gg[bi];
                        if (rr < remR && rr + h >= remR) {
                            s_sel[0] = (unsigned)(4 * lane + bi);
                            s_sel[1] = remR - rr;
                        }
                        rr += h;
                    }
                }
                __syncthreads();
                prefix = (prefix << 8) | s_sel[0];
                remR = s_sel[1];
            }
            const unsigned int T = prefix;
            unsigned int local = 0;
            for (int u = 0; u < ITEMS; ++u) {
                const int i = t * ITEMS + u;
                if (s_exp[i] == 255 && orderkey(pj[i]) == T) ++local;
            }
            unsigned int inc = local;
#pragma unroll
            for (int off = 1; off < 64; off <<= 1) {
                const unsigned int vv = __shfl_up(inc, off, 64);
                if (lane >= off) inc += vv;
            }
            if (lane == 63) s_wsum[wv] = inc;
            __syncthreads();
            if (t < 16) {
                unsigned int a2 = 0;
                for (int w2 = 0; w2 < t; ++w2) a2 += s_wsum[w2];
                s_wsum[16 + t] = a2;
            }
            __syncthreads();
            unsigned int taken = (inc - local) + s_wsum[16 + wv];
            for (int u = 0; u < ITEMS; ++u) {
                const int i = t * ITEMS + u;
                if (s_exp[i] != 255) continue;
                const unsigned int key = orderkey(pj[i]);
                if (key > T) {
                    s_exp[i] = (unsigned char)j;
                } else if (key == T) {
                    if (taken < remR) s_exp[i] = (unsigned char)j;
                    ++taken;
                }
            }
            __syncthreads();
        }
        nun -= kk;
    }

    float* out_mask = out;
    float* out_p = out + (size_t)BN;
    for (int u = 0; u < ITEMS; ++u) {
        const int i = t * ITEMS + u;
        int e = s_exp[i];
        if (e == 255) e = 0;
        out_mask[(size_t)b * N + i] = (float)e;
        out_p[(size_t)b * N + i] = probs_t[((size_t)b * E + e) * N + i];
    }
}

}  // namespace

extern "C" void kernel_launch(void* const* d_in, const int* in_sizes, int n_in,
                              void* d_out, int out_size, void* d_ws, size_t ws_size,
                              hipStream_t stream) {
    const float* x = (const float*)d_in[0];     // [B, N, D]
    const float* W = (const float*)d_in[1];     // [E, D]
    const float* bias = (const float*)d_in[2];  // [E]
    float* out = (float*)d_out;                 // [2*B*N] floats
    float* probs_t = (float*)d_ws;              // [B, E, N] fp32, 1 MB

    probs_kernel<<<BN / 64, 256, 0, stream>>>(x, W, bias, probs_t);
    route_kernel<<<B, 1024, 0, stream>>>(probs_t, out);
}